// Round 5
// baseline (331.146 us; speedup 1.0000x reference)
//
#include <hip/hip_runtime.h>
#include <math.h>

#define HH 224
#define WW 224
#define TH 32
#define TW 32
#define TILES_X 7
#define TILES_PER_IMG 49
#define HALO 36
#define BOXH 56
#define BOXW 57          // LDS stride for the source box
#define TMPS 37          // LDS stride for Tmp (aliased onto Box)

struct __align__(16) ImgParams {
    float ca, sa, ay, by;   // rotation + y-affine (sy = ay*yr + by)
    float ax, bx, w0, w1;   // x-affine (flip folded in) + blur taps
    float w2, w3, w4, pad;
};

// ---------------- mask: which channels are augmented ----------------
__global__ void mask_kernel(const int* __restrict__ channel_idx, int n_aug, int c,
                            int* __restrict__ mask) {
    int t = threadIdx.x;
    for (int i = t; i < c; i += blockDim.x) mask[i] = 0;
    __syncthreads();
    for (int i = t; i < n_aug; i += blockDim.x) mask[channel_idx[i]] = 1;
}

// ---------------- per-image params: all transcendentals, once per image ----------------
__global__ void params_kernel(const float* __restrict__ aug_u,
                              ImgParams* __restrict__ params, int N) {
    int n = blockIdx.x * blockDim.x + threadIdx.x;
    if (n >= N) return;
    const float* u = aug_u + (size_t)n * 7;
    const float u0 = u[0], u1 = u[1], u2 = u[2], u3 = u[3], u4 = u[4], u5 = u[5], u6 = u[6];

    const float area  = (float)(HH * WW) * (0.8f + 0.2f * u0);
    const float lo    = logf(0.75f);
    const float hi    = logf(4.0f / 3.0f);
    const float ratio = expf(lo + (hi - lo) * u1);
    float wc = sqrtf(area * ratio);
    float hc = sqrtf(area / ratio);
    wc = fminf(fmaxf(wc, 1.0f), (float)WW);
    hc = fminf(fmaxf(hc, 1.0f), (float)HH);
    const float fi    = u2 * ((float)HH - hc);
    const float fj    = u3 * ((float)WW - wc);
    const bool  flip  = u4 < 0.5f;
    const float angle = u5 * 3.14159274101257324f;
    const float sigma = 0.1f + 1.9f * u6;

    ImgParams p;
    p.ca = cosf(angle);
    p.sa = sinf(angle);
    const float syk = hc / (float)HH;
    const float sxk = wc / (float)WW;
    p.ay = syk;
    p.by = 0.5f * syk - 0.5f + fi;
    if (flip) {
        p.ax = -sxk;
        p.bx = ((float)WW - 0.5f) * sxk - 0.5f + fj;
    } else {
        p.ax = sxk;
        p.bx = 0.5f * sxk - 0.5f + fj;
    }
    float wk[5], wsum = 0.f;
    const float inv2s2 = 1.0f / (2.0f * sigma * sigma);
    #pragma unroll
    for (int k = 0; k < 5; ++k) {
        float d = (float)k - 2.0f;
        wk[k] = expf(-(d * d) * inv2s2);
        wsum += wk[k];
    }
    float inv = 1.0f / wsum;
    p.w0 = wk[0] * inv; p.w1 = wk[1] * inv; p.w2 = wk[2] * inv;
    p.w3 = wk[3] * inv; p.w4 = wk[4] * inv;
    p.pad = 0.f;
    params[n] = p;
}

// ---------------- copy non-augmented channels, float4 ----------------
__global__ __launch_bounds__(256) void copy_kernel(const float4* __restrict__ M4,
                                                   const int* __restrict__ mask,
                                                   float4* __restrict__ out4,
                                                   int c, int bpc) {
    int chan = blockIdx.x / bpc;
    int blk  = blockIdx.x % bpc;
    int ch   = chan % c;
    if (mask[ch]) return;
    int off = blk * 256 + threadIdx.x;
    size_t idx = (size_t)chan * (HH * WW / 4) + off;
    out4[idx] = M4[idx];
}

// ---------------- fused warp + blur + noise per 32x32 tile ----------------
__global__ __launch_bounds__(256) void augment_kernel(
        const float* __restrict__ M, const int* __restrict__ channel_idx,
        const ImgParams* __restrict__ params, const float* __restrict__ noise,
        float* __restrict__ out, int c, int n_aug) {
    const int tile = blockIdx.x;            // 0..48
    const int a    = blockIdx.y;            // 0..n_aug-1
    const int bi   = blockIdx.z;            // 0..b-1
    const int n    = bi * n_aug + a;
    const int ch   = channel_idx[a];
    const int ty   = tile / TILES_X;
    const int y0   = ty * TH;
    const int x0   = (tile - ty * TILES_X) * TW;
    const int tid  = threadIdx.x;

    const ImgParams P = params[n];          // uniform -> scalar loads
    const float* __restrict__ img = M + ((size_t)bi * c + ch) * (HH * WW);

    __shared__ float Box[BOXH * BOXW];      // 12.5 KB; aliased as Tmp after gather
    __shared__ float Wt[HALO][HALO + 1];    // 5.2 KB

    const float cc = 111.5f;

    // ---- bounding box of source coords (block-uniform scalar math) ----
    // halo coords vy in [y0-2, y0+33]; reflected values stay within the clamped range
    const int ry_lo = max(y0 - 2, 0),  ry_hi = min(y0 + 33, HH - 1);
    const int rx_lo = max(x0 - 2, 0),  rx_hi = min(x0 + 33, WW - 1);
    const float dyl = (float)ry_lo - cc, dyh = (float)ry_hi - cc;
    const float dxl = (float)rx_lo - cc, dxh = (float)rx_hi - cc;
    // yr = ca*dy + sa*dx + cc  (sa >= 0, since angle in [0,pi])
    float yr_min = cc + fminf(P.ca * dyl, P.ca * dyh) + P.sa * dxl;
    float yr_max = cc + fmaxf(P.ca * dyl, P.ca * dyh) + P.sa * dxh;
    // xr = ca*dx - sa*dy + cc
    float xr_min = cc + fminf(P.ca * dxl, P.ca * dxh) - P.sa * dyh;
    float xr_max = cc + fmaxf(P.ca * dxl, P.ca * dxh) - P.sa * dyl;
    // only in-bounds (inb) samples ever read memory -> tighten to valid window
    yr_min = fmaxf(yr_min, -0.5f); yr_max = fminf(yr_max, (float)HH - 0.5f);
    xr_min = fmaxf(xr_min, -0.5f); xr_max = fminf(xr_max, (float)WW - 0.5f);
    // sy monotone in yr (ay>=0); sx monotone in xr with sign of ax
    const float sy_min = P.ay * yr_min + P.by, sy_max = P.ay * yr_max + P.by;
    const float sx_a = P.ax * xr_min + P.bx,  sx_b = P.ax * xr_max + P.bx;
    const float sx_min = fminf(sx_a, sx_b),   sx_max = fmaxf(sx_a, sx_b);
    const int by0 = min(max((int)floorf(sy_min), 0), HH - 1);
    const int by1 = min(max((int)floorf(sy_max) + 1, 0), HH - 1);
    const int bx0 = min(max((int)floorf(sx_min), 0), WW - 1);
    const int bx1 = min(max((int)floorf(sx_max) + 1, 0), WW - 1);
    const int bh = max(by1 - by0 + 1, 0);   // <= 52 (35*sqrt2 + 2)
    const int bw = bx1 - bx0 + 1;           // <= 52

    // ---- coalesced load of the box into LDS (one row per wave) ----
    {
        const float* bimg = img + by0 * WW + bx0;
        const int q = tid & 63;
        for (int r = tid >> 6; r < bh; r += 4)
            if (q < bw) Box[r * BOXW + q] = bimg[r * WW + q];
    }
    __syncthreads();

    // ---- warp into halo tile, bilinear from LDS box ----
    {
        int hy = tid / HALO, hx = tid - hy * HALO;
        #pragma unroll
        for (int it = 0; it < 6; ++it) {
            int idx = it * 256 + tid;
            if (idx < HALO * HALO) {
                int vy = y0 + hy - 2;
                int vx = x0 + hx - 2;
                int ayv = abs(vy);  int ry = min(ayv, 2 * (HH - 1) - ayv);  // reflect
                int axv = abs(vx);  int rx = min(axv, 2 * (WW - 1) - axv);
                float dy = (float)ry - cc, dx = (float)rx - cc;
                float yr = P.ca * dy + P.sa * dx + cc;
                float xr = P.ca * dx - P.sa * dy + cc;
                float val = 0.f;
                if (yr >= -0.5f && yr <= (float)HH - 0.5f &&
                    xr >= -0.5f && xr <= (float)WW - 0.5f) {
                    float sy = P.ay * yr + P.by;
                    float sx = P.ax * xr + P.bx;
                    float fy = floorf(sy), fx = floorf(sx);
                    float wy = sy - fy, wx = sx - fx;
                    int yi = min(max((int)fy, 0), HH - 1);
                    int xi = min(max((int)fx, 0), WW - 1);
                    int dyi = (min(yi + 1, HH - 1) - yi) * BOXW;  // 0 or BOXW
                    int dxi =  min(xi + 1, WW - 1) - xi;          // 0 or 1
                    int k = (yi - by0) * BOXW + (xi - bx0);
                    float v00 = Box[k],       v01 = Box[k + dxi];
                    float v10 = Box[k + dyi], v11 = Box[k + dyi + dxi];
                    float top = v00 + (v01 - v00) * wx;
                    float bot = v10 + (v11 - v10) * wx;
                    val = top + (bot - top) * wy;
                }
                Wt[hy][hx] = val;
            }
            hy += 7; hx += 4; if (hx >= HALO) { hx -= HALO; hy += 1; }
        }
    }
    __syncthreads();

    // ---- vertical blur: 32 rows x 36 cols (Tmp aliases Box; safe after barrier) ----
    float* __restrict__ Tmp = Box;
    {
        int vy = tid / HALO, vx = tid - vy * HALO;
        #pragma unroll
        for (int it = 0; it < 5; ++it) {
            int idx = it * 256 + tid;
            if (idx < TH * HALO) {
                float s = P.w0 * Wt[vy][vx]     + P.w1 * Wt[vy + 1][vx]
                        + P.w2 * Wt[vy + 2][vx] + P.w3 * Wt[vy + 3][vx]
                        + P.w4 * Wt[vy + 4][vx];
                Tmp[vy * TMPS + vx] = s;
            }
            vy += 7; vx += 4; if (vx >= HALO) { vx -= HALO; vy += 1; }
        }
    }
    __syncthreads();

    // ---- horizontal blur + noise + write ----
    const float* __restrict__ npz = noise + (size_t)n * (HH * WW);
    float* __restrict__ op = out + ((size_t)bi * c + ch) * (HH * WW);
    #pragma unroll
    for (int it = 0; it < 4; ++it) {
        int idx = it * 256 + tid;
        int y = idx >> 5, x = idx & 31;
        const float* t = Tmp + y * TMPS + x;
        float s = P.w0 * t[0] + P.w1 * t[1] + P.w2 * t[2] + P.w3 * t[3] + P.w4 * t[4];
        int gy = y0 + y, gx = x0 + x;
        size_t o = (size_t)gy * WW + gx;
        op[o] = s + 0.05f * npz[o];
    }
}

extern "C" void kernel_launch(void* const* d_in, const int* in_sizes, int n_in,
                              void* d_out, int out_size, void* d_ws, size_t ws_size,
                              hipStream_t stream) {
    const float* M           = (const float*)d_in[0];
    const int*   channel_idx = (const int*)d_in[1];
    const float* aug_u       = (const float*)d_in[2];
    const float* noise       = (const float*)d_in[3];
    float* out = (float*)d_out;

    const int n_aug = in_sizes[1];
    const int b     = in_sizes[2] / (n_aug * 7);
    const int c     = in_sizes[0] / (b * HH * WW);
    const int N     = b * n_aug;

    int* mask = (int*)d_ws;
    ImgParams* params = (ImgParams*)((char*)d_ws + 4096);

    mask_kernel<<<1, 256, 0, stream>>>(channel_idx, n_aug, c, mask);
    params_kernel<<<(N + 255) / 256, 256, 0, stream>>>(aug_u, params, N);

    const int nchan = b * c;
    const int bpc   = (HH * WW / 4 + 255) / 256;  // 49 blocks per channel
    copy_kernel<<<nchan * bpc, 256, 0, stream>>>((const float4*)M, mask, (float4*)out, c, bpc);

    dim3 grid(TILES_PER_IMG, n_aug, b);
    augment_kernel<<<grid, 256, 0, stream>>>(M, channel_idx, params, noise, out, c, n_aug);
}

// Round 7
// 309.410 us; speedup vs baseline: 1.0703x; 1.0703x over previous
//
#include <hip/hip_runtime.h>
#include <math.h>

#define HH 224
#define WW 224
#define TH 32
#define TW 32
#define TILES_X 7
#define HALO 36
#define BOXH 56
#define BOXW 57          // LDS stride for the source box
#define WTS  38          // even stride -> float2-aligned rows
#define TMPS 38

struct __align__(16) ImgParams {
    float ca, sa, ay, by;   // rotation + y-affine (sy = ay*yr + by)
    float ax, bx, w0, w1;   // x-affine (flip folded in) + blur taps
    float w2, w3, w4, pad;
};

// ---------------- amap: channel -> augment index (or -1) ----------------
__global__ void amap_kernel(const int* __restrict__ channel_idx, int n_aug, int c,
                            int* __restrict__ amap) {
    int t = threadIdx.x;
    for (int i = t; i < c; i += blockDim.x) amap[i] = -1;
    __syncthreads();
    for (int i = t; i < n_aug; i += blockDim.x) amap[channel_idx[i]] = i;
}

// ---------------- per-image params: all transcendentals, once per image ----------------
__global__ void params_kernel(const float* __restrict__ aug_u,
                              ImgParams* __restrict__ params, int N) {
    int n = blockIdx.x * blockDim.x + threadIdx.x;
    if (n >= N) return;
    const float* u = aug_u + (size_t)n * 7;
    const float u0 = u[0], u1 = u[1], u2 = u[2], u3 = u[3], u4 = u[4], u5 = u[5], u6 = u[6];

    const float area  = (float)(HH * WW) * (0.8f + 0.2f * u0);
    const float lo    = logf(0.75f);
    const float hi    = logf(4.0f / 3.0f);
    const float ratio = expf(lo + (hi - lo) * u1);
    float wc = sqrtf(area * ratio);
    float hc = sqrtf(area / ratio);
    wc = fminf(fmaxf(wc, 1.0f), (float)WW);
    hc = fminf(fmaxf(hc, 1.0f), (float)HH);
    const float fi    = u2 * ((float)HH - hc);
    const float fj    = u3 * ((float)WW - wc);
    const bool  flip  = u4 < 0.5f;
    const float angle = u5 * 3.14159274101257324f;
    const float sigma = 0.1f + 1.9f * u6;

    ImgParams p;
    p.ca = cosf(angle);
    p.sa = sinf(angle);
    const float syk = hc / (float)HH;
    const float sxk = wc / (float)WW;
    p.ay = syk;
    p.by = 0.5f * syk - 0.5f + fi;
    if (flip) {
        p.ax = -sxk;
        p.bx = ((float)WW - 0.5f) * sxk - 0.5f + fj;
    } else {
        p.ax = sxk;
        p.bx = 0.5f * sxk - 0.5f + fj;
    }
    float wk[5], wsum = 0.f;
    const float inv2s2 = 1.0f / (2.0f * sigma * sigma);
    #pragma unroll
    for (int k = 0; k < 5; ++k) {
        float d = (float)k - 2.0f;
        wk[k] = expf(-(d * d) * inv2s2);
        wsum += wk[k];
    }
    float inv = 1.0f / wsum;
    p.w0 = wk[0] * inv; p.w1 = wk[1] * inv; p.w2 = wk[2] * inv;
    p.w3 = wk[3] * inv; p.w4 = wk[4] * inv;
    p.pad = 0.f;
    params[n] = p;
}

// ---------------- fused: copy (non-aug) OR warp+blur+noise (aug) ----------------
__global__ __launch_bounds__(256) void fused_kernel(
        const float* __restrict__ M, const int* __restrict__ amap,
        const ImgParams* __restrict__ params, const float* __restrict__ noise,
        float* __restrict__ out, int c, int n_aug) {
    const int tile = blockIdx.x;            // 0..48
    const int ch   = blockIdx.y;            // 0..c-1
    const int bi   = blockIdx.z;            // 0..b-1
    const int tid  = threadIdx.x;
    const int a    = amap[ch];
    const size_t chanoff = ((size_t)bi * c + ch) * (HH * WW);

    if (a < 0) {
        // -------- copy path: 49 blocks x 256 float4 == 224*224 floats --------
        const float4* __restrict__ src = (const float4*)(M + chanoff);
        float4* __restrict__ dst = (float4*)(out + chanoff);
        int off = tile * 256 + tid;
        dst[off] = src[off];
        return;
    }

    // -------- augment path --------
    const int n  = bi * n_aug + a;
    const int ty = tile / TILES_X;
    const int y0 = ty * TH;
    const int x0 = (tile - ty * TILES_X) * TW;

    const ImgParams P = params[n];          // uniform -> scalar loads
    const float* __restrict__ img = M + chanoff;

    __shared__ float Box[BOXH * BOXW];      // 12.8 KB; aliased as Tmp after warp
    __shared__ float Wt[HALO][WTS];         // 5.5 KB

    const float cc = 111.5f;

    // ---- bounding box of source coords (block-uniform scalar math) ----
    const int ry_lo = max(y0 - 2, 0),  ry_hi = min(y0 + 33, HH - 1);
    const int rx_lo = max(x0 - 2, 0),  rx_hi = min(x0 + 33, WW - 1);
    const float dyl = (float)ry_lo - cc, dyh = (float)ry_hi - cc;
    const float dxl = (float)rx_lo - cc, dxh = (float)rx_hi - cc;
    float yr_min = cc + fminf(P.ca * dyl, P.ca * dyh) + P.sa * dxl;
    float yr_max = cc + fmaxf(P.ca * dyl, P.ca * dyh) + P.sa * dxh;
    float xr_min = cc + fminf(P.ca * dxl, P.ca * dxh) - P.sa * dyh;
    float xr_max = cc + fmaxf(P.ca * dxl, P.ca * dxh) - P.sa * dyl;
    yr_min = fmaxf(yr_min, -0.5f); yr_max = fminf(yr_max, (float)HH - 0.5f);
    xr_min = fmaxf(xr_min, -0.5f); xr_max = fminf(xr_max, (float)WW - 0.5f);
    const float sy_min = P.ay * yr_min + P.by, sy_max = P.ay * yr_max + P.by;
    const float sx_a = P.ax * xr_min + P.bx,  sx_b = P.ax * xr_max + P.bx;
    const float sx_min = fminf(sx_a, sx_b), sx_max = fmaxf(sx_a, sx_b);
    const int by0 = min(max((int)floorf(sy_min), 0), HH - 1);
    const int by1 = min(max((int)floorf(sy_max) + 1, 0), HH - 1);
    const int bx0 = min(max((int)floorf(sx_min), 0), WW - 1);
    const int bx1 = min(max((int)floorf(sx_max) + 1, 0), WW - 1);
    const int bh = max(by1 - by0 + 1, 0);   // <= 52
    const int bw = bx1 - bx0 + 1;           // <= 52

    // ---- coalesced load of the box into LDS ----
    {
        const float* bimg = img + by0 * WW + bx0;
        const int q = tid & 63;
        for (int r = tid >> 6; r < bh; r += 4)
            if (q < bw) Box[r * BOXW + q] = bimg[r * WW + q];
    }
    __syncthreads();

    // ---- warp into halo tile: thread = (row, 6 consecutive x) ----
    // NOTE: per-sample math below uses the EXACT reference association
    // (yr = ca*dy + sa*dx + cc, explicit range check) — feeding the
    // discontinuous inb/zero-fill decision; do NOT re-associate (round-6 fail).
    if (tid < 216) {
        const int hy  = tid / 6;
        const int g   = tid - hy * 6;
        const int hx0 = g * 6;
        int vy = y0 + hy - 2;
        int ayv = abs(vy);
        int ry = min(ayv, 2 * (HH - 1) - ayv);   // reflect
        const float dy = (float)ry - cc;
        const int kbase = -(by0 * BOXW + bx0);
        float acc[6];
        #pragma unroll
        for (int j = 0; j < 6; ++j) {
            int vx = x0 + hx0 + j - 2;
            int axv = abs(vx);
            int rx = min(axv, 2 * (WW - 1) - axv);
            float dx = (float)rx - cc;
            float yr = P.ca * dy + P.sa * dx + cc;
            float xr = P.ca * dx - P.sa * dy + cc;
            float val = 0.f;
            if (yr >= -0.5f && yr <= (float)HH - 0.5f &&
                xr >= -0.5f && xr <= (float)WW - 0.5f) {
                float sy = P.ay * yr + P.by;
                float sx = P.ax * xr + P.bx;
                float fy = floorf(sy), fx = floorf(sx);
                float wy = sy - fy, wx = sx - fx;
                int yi = min(max((int)fy, 0), HH - 1);
                int xi = min(max((int)fx, 0), WW - 1);
                int dyi = (min(yi + 1, HH - 1) - yi) * BOXW;   // 0 or BOXW
                int dxi =  min(xi + 1, WW - 1) - xi;           // 0 or 1
                int k = yi * BOXW + xi + kbase;
                float v00 = Box[k],       v01 = Box[k + dxi];
                float v10 = Box[k + dyi], v11 = Box[k + dyi + dxi];
                float top = v00 + (v01 - v00) * wx;
                float bot = v10 + (v11 - v10) * wx;
                val = top + (bot - top) * wy;
            }
            acc[j] = val;
        }
        float2* wrow = (float2*)&Wt[hy][hx0];
        wrow[0] = make_float2(acc[0], acc[1]);
        wrow[1] = make_float2(acc[2], acc[3]);
        wrow[2] = make_float2(acc[4], acc[5]);
    }
    __syncthreads();

    // ---- vertical blur: 32 rows x 18 col-pairs, float2 ----
    float* __restrict__ Tmp = Box;   // alias; safe after barrier
    for (int u = tid; u < TH * 18; u += 256) {
        int vy = u / 18, vp = u - vy * 18;
        int x2 = 2 * vp;
        float2 a0 = *(const float2*)&Wt[vy][x2];
        float2 a1 = *(const float2*)&Wt[vy + 1][x2];
        float2 a2 = *(const float2*)&Wt[vy + 2][x2];
        float2 a3 = *(const float2*)&Wt[vy + 3][x2];
        float2 a4 = *(const float2*)&Wt[vy + 4][x2];
        float2 s;
        s.x = P.w0 * a0.x + P.w1 * a1.x + P.w2 * a2.x + P.w3 * a3.x + P.w4 * a4.x;
        s.y = P.w0 * a0.y + P.w1 * a1.y + P.w2 * a2.y + P.w3 * a3.y + P.w4 * a4.y;
        *(float2*)&Tmp[vy * TMPS + x2] = s;
    }
    __syncthreads();

    // ---- horizontal blur + noise + write, 2 pixels/thread ----
    const float* __restrict__ npz = noise + (size_t)n * (HH * WW);
    float* __restrict__ op = out + chanoff;
    #pragma unroll
    for (int it = 0; it < 2; ++it) {
        int u = it * 256 + tid;          // 0..511
        int yy = u >> 4, p = u & 15;     // 32 rows x 16 pairs
        int x = 2 * p;
        const float* t = Tmp + yy * TMPS + x;
        float2 t01 = *(const float2*)(t);
        float2 t23 = *(const float2*)(t + 2);
        float2 t45 = *(const float2*)(t + 4);
        float s0 = P.w0 * t01.x + P.w1 * t01.y + P.w2 * t23.x + P.w3 * t23.y + P.w4 * t45.x;
        float s1 = P.w0 * t01.y + P.w1 * t23.x + P.w2 * t23.y + P.w3 * t45.x + P.w4 * t45.y;
        int gy = y0 + yy, gx = x0 + x;
        size_t o = (size_t)gy * WW + gx;
        float2 nz = *(const float2*)(npz + o);
        *(float2*)(op + o) = make_float2(s0 + 0.05f * nz.x, s1 + 0.05f * nz.y);
    }
}

extern "C" void kernel_launch(void* const* d_in, const int* in_sizes, int n_in,
                              void* d_out, int out_size, void* d_ws, size_t ws_size,
                              hipStream_t stream) {
    const float* M           = (const float*)d_in[0];
    const int*   channel_idx = (const int*)d_in[1];
    const float* aug_u       = (const float*)d_in[2];
    const float* noise       = (const float*)d_in[3];
    float* out = (float*)d_out;

    const int n_aug = in_sizes[1];
    const int b     = in_sizes[2] / (n_aug * 7);
    const int c     = in_sizes[0] / (b * HH * WW);
    const int N     = b * n_aug;

    int* amap = (int*)d_ws;
    ImgParams* params = (ImgParams*)((char*)d_ws + 4096);

    amap_kernel<<<1, 256, 0, stream>>>(channel_idx, n_aug, c, amap);
    params_kernel<<<(N + 255) / 256, 256, 0, stream>>>(aug_u, params, N);

    dim3 grid(49, c, b);
    fused_kernel<<<grid, 256, 0, stream>>>(M, amap, params, noise, out, c, n_aug);
}

// Round 8
// 222.273 us; speedup vs baseline: 1.4898x; 1.3920x over previous
//
#include <hip/hip_runtime.h>
#include <math.h>

#define HH 224
#define WW 224
#define TH 32
#define TW 32
#define TILES_X 7
#define HALO 36
#define BOXH 56
#define BOXW 57          // LDS stride for the source box (padded +1 row/col used)
#define WTS  40          // 160B rows -> float4-aligned
#define TMPS 40

struct __align__(16) ImgParams {
    float ca, sa, ay, by;   // rotation + y-affine (sy = ay*yr + by)
    float ax, bx, w0, w1;   // x-affine (flip folded in) + blur taps
    float w2, w3, w4, pad;
};

// ---------------- amap: channel -> augment index (or -1) ----------------
__global__ void amap_kernel(const int* __restrict__ channel_idx, int n_aug, int c,
                            int* __restrict__ amap) {
    int t = threadIdx.x;
    for (int i = t; i < c; i += blockDim.x) amap[i] = -1;
    __syncthreads();
    for (int i = t; i < n_aug; i += blockDim.x) amap[channel_idx[i]] = i;
}

// ---------------- per-image params: all transcendentals, once per image ----------------
__global__ void params_kernel(const float* __restrict__ aug_u,
                              ImgParams* __restrict__ params, int N) {
    int n = blockIdx.x * blockDim.x + threadIdx.x;
    if (n >= N) return;
    const float* u = aug_u + (size_t)n * 7;
    const float u0 = u[0], u1 = u[1], u2 = u[2], u3 = u[3], u4 = u[4], u5 = u[5], u6 = u[6];

    const float area  = (float)(HH * WW) * (0.8f + 0.2f * u0);
    const float lo    = logf(0.75f);
    const float hi    = logf(4.0f / 3.0f);
    const float ratio = expf(lo + (hi - lo) * u1);
    float wc = sqrtf(area * ratio);
    float hc = sqrtf(area / ratio);
    wc = fminf(fmaxf(wc, 1.0f), (float)WW);
    hc = fminf(fmaxf(hc, 1.0f), (float)HH);
    const float fi    = u2 * ((float)HH - hc);
    const float fj    = u3 * ((float)WW - wc);
    const bool  flip  = u4 < 0.5f;
    const float angle = u5 * 3.14159274101257324f;
    const float sigma = 0.1f + 1.9f * u6;

    ImgParams p;
    p.ca = cosf(angle);
    p.sa = sinf(angle);
    const float syk = hc / (float)HH;
    const float sxk = wc / (float)WW;
    p.ay = syk;
    p.by = 0.5f * syk - 0.5f + fi;
    if (flip) {
        p.ax = -sxk;
        p.bx = ((float)WW - 0.5f) * sxk - 0.5f + fj;
    } else {
        p.ax = sxk;
        p.bx = 0.5f * sxk - 0.5f + fj;
    }
    float wk[5], wsum = 0.f;
    const float inv2s2 = 1.0f / (2.0f * sigma * sigma);
    #pragma unroll
    for (int k = 0; k < 5; ++k) {
        float d = (float)k - 2.0f;
        wk[k] = expf(-(d * d) * inv2s2);
        wsum += wk[k];
    }
    float inv = 1.0f / wsum;
    p.w0 = wk[0] * inv; p.w1 = wk[1] * inv; p.w2 = wk[2] * inv;
    p.w3 = wk[3] * inv; p.w4 = wk[4] * inv;
    p.pad = 0.f;
    params[n] = p;
}

// ---------------- fused: copy (non-aug) OR warp+blur+noise (aug) ----------------
__global__ __launch_bounds__(256) void fused_kernel(
        const float* __restrict__ M, const int* __restrict__ amap,
        const ImgParams* __restrict__ params, const float* __restrict__ noise,
        float* __restrict__ out, int c, int n_aug) {
    const int tile = blockIdx.x;            // 0..48
    const int ch   = blockIdx.y;            // 0..c-1
    const int bi   = blockIdx.z;            // 0..b-1
    const int tid  = threadIdx.x;
    const int a    = amap[ch];
    const size_t chanoff = ((size_t)bi * c + ch) * (HH * WW);

    if (a < 0) {
        // -------- copy path: 49 blocks x 256 float4 == 224*224 floats --------
        const float4* __restrict__ src = (const float4*)(M + chanoff);
        float4* __restrict__ dst = (float4*)(out + chanoff);
        int off = tile * 256 + tid;
        dst[off] = src[off];
        return;
    }

    // -------- augment path --------
    const int n  = bi * n_aug + a;
    const int ty = tile / TILES_X;
    const int y0 = ty * TH;
    const int x0 = (tile - ty * TILES_X) * TW;

    const ImgParams P = params[n];          // uniform -> scalar loads
    const float* __restrict__ img = M + chanoff;

    __shared__ __align__(16) float Box[BOXH * BOXW];   // 12.8 KB; aliased as Tmp later
    __shared__ __align__(16) float Wt[HALO][WTS];      // 5.8 KB

    const float cc = 111.5f;

    // ---- bounding box of source coords (block-uniform scalar math) ----
    const int ry_lo = max(y0 - 2, 0),  ry_hi = min(y0 + 33, HH - 1);
    const int rx_lo = max(x0 - 2, 0),  rx_hi = min(x0 + 33, WW - 1);
    const float dyl = (float)ry_lo - cc, dyh = (float)ry_hi - cc;
    const float dxl = (float)rx_lo - cc, dxh = (float)rx_hi - cc;
    float yr_min = cc + fminf(P.ca * dyl, P.ca * dyh) + P.sa * dxl;
    float yr_max = cc + fmaxf(P.ca * dyl, P.ca * dyh) + P.sa * dxh;
    float xr_min = cc + fminf(P.ca * dxl, P.ca * dxh) - P.sa * dyh;
    float xr_max = cc + fmaxf(P.ca * dxl, P.ca * dxh) - P.sa * dyl;
    yr_min = fmaxf(yr_min, -0.5f); yr_max = fminf(yr_max, (float)HH - 0.5f);
    xr_min = fmaxf(xr_min, -0.5f); xr_max = fminf(xr_max, (float)WW - 0.5f);
    const float sy_min = P.ay * yr_min + P.by, sy_max = P.ay * yr_max + P.by;
    const float sx_a = P.ax * xr_min + P.bx,  sx_b = P.ax * xr_max + P.bx;
    const float sx_min = fminf(sx_a, sx_b), sx_max = fmaxf(sx_a, sx_b);
    const int by0 = min(max((int)floorf(sy_min), 0), HH - 1);
    const int by1 = min(max((int)floorf(sy_max) + 1, 0), HH - 1);
    const int bx0 = min(max((int)floorf(sx_min), 0), WW - 1);
    const int bx1 = min(max((int)floorf(sx_max) + 1, 0), WW - 1);
    const int bh = max(by1 - by0 + 1, 0);   // <= 52 rows of real data
    const int bw = bx1 - bx0 + 1;           // <= 52 cols

    // ---- coalesced load of the box into LDS, padded +1 row/col (clamped src) ----
    // Padding makes the bilinear neighbors constant offsets (+1, +BOXW, +BOXW+1),
    // values bit-identical to the reference's index clamp.
    {
        const int q = tid & 63;
        if (q <= bw) {
            int scol = min(bx0 + q, WW - 1);
            for (int r = tid >> 6; r <= bh; r += 4) {
                int srow = min(by0 + r, HH - 1);
                Box[r * BOXW + q] = img[srow * WW + scol];
            }
        }
    }
    __syncthreads();

    // ---- warp into halo tile: thread = (row, 6 consecutive x) ----
    // NOTE: per-sample math uses the EXACT reference association
    // (yr = ca*dy + sa*dx + cc, explicit range check) — feeding the
    // discontinuous inb/zero-fill decision; do NOT re-associate (round-6 fail).
    if (tid < 216) {
        const int hy  = tid / 6;
        const int g   = tid - hy * 6;
        const int hx0 = g * 6;
        int vy = y0 + hy - 2;
        int ayv = abs(vy);
        int ry = min(ayv, 2 * (HH - 1) - ayv);   // reflect
        const float dy = (float)ry - cc;
        const int kbase = -(by0 * BOXW + bx0);
        float acc[6];
        #pragma unroll
        for (int j = 0; j < 6; ++j) {
            int vx = x0 + hx0 + j - 2;
            int axv = abs(vx);
            int rx = min(axv, 2 * (WW - 1) - axv);
            float dx = (float)rx - cc;
            float yr = P.ca * dy + P.sa * dx + cc;
            float xr = P.ca * dx - P.sa * dy + cc;
            float val = 0.f;
            if (yr >= -0.5f && yr <= (float)HH - 0.5f &&
                xr >= -0.5f && xr <= (float)WW - 0.5f) {
                float sy = P.ay * yr + P.by;
                float sx = P.ax * xr + P.bx;
                float fy = floorf(sy), fx = floorf(sx);
                float wy = sy - fy, wx = sx - fx;
                int yi = min(max((int)fy, 0), HH - 1);
                int xi = min(max((int)fx, 0), WW - 1);
                int k = yi * BOXW + xi + kbase;
                float v00 = Box[k],        v01 = Box[k + 1];
                float v10 = Box[k + BOXW], v11 = Box[k + BOXW + 1];
                float top = v00 + (v01 - v00) * wx;
                float bot = v10 + (v11 - v10) * wx;
                val = top + (bot - top) * wy;
            }
            acc[j] = val;
        }
        float2* wrow = (float2*)&Wt[hy][hx0];
        wrow[0] = make_float2(acc[0], acc[1]);
        wrow[1] = make_float2(acc[2], acc[3]);
        wrow[2] = make_float2(acc[4], acc[5]);
    }
    __syncthreads();

    // ---- vertical blur: 32 rows x 9 col-quads, float4 ----
    float* __restrict__ Tmp = Box;   // alias; safe after barrier
    for (int u = tid; u < TH * 9; u += 256) {
        int vy = u / 9, q = u - vy * 9;
        int x = 4 * q;
        float4 a0 = *(const float4*)&Wt[vy][x];
        float4 a1 = *(const float4*)&Wt[vy + 1][x];
        float4 a2 = *(const float4*)&Wt[vy + 2][x];
        float4 a3 = *(const float4*)&Wt[vy + 3][x];
        float4 a4 = *(const float4*)&Wt[vy + 4][x];
        float4 s;
        s.x = P.w0 * a0.x + P.w1 * a1.x + P.w2 * a2.x + P.w3 * a3.x + P.w4 * a4.x;
        s.y = P.w0 * a0.y + P.w1 * a1.y + P.w2 * a2.y + P.w3 * a3.y + P.w4 * a4.y;
        s.z = P.w0 * a0.z + P.w1 * a1.z + P.w2 * a2.z + P.w3 * a3.z + P.w4 * a4.z;
        s.w = P.w0 * a0.w + P.w1 * a1.w + P.w2 * a2.w + P.w3 * a3.w + P.w4 * a4.w;
        *(float4*)&Tmp[vy * TMPS + x] = s;
    }
    __syncthreads();

    // ---- horizontal blur + noise + write, 4 px/thread, float4 ----
    const float* __restrict__ npz = noise + (size_t)n * (HH * WW);
    float* __restrict__ op = out + chanoff;
    {
        int yy = tid >> 3, p = tid & 7;
        int x = 4 * p;
        const float* t = Tmp + yy * TMPS + x;
        float4 ta = *(const float4*)(t);       // t0..t3
        float4 tb = *(const float4*)(t + 4);   // t4..t7
        float s0 = P.w0 * ta.x + P.w1 * ta.y + P.w2 * ta.z + P.w3 * ta.w + P.w4 * tb.x;
        float s1 = P.w0 * ta.y + P.w1 * ta.z + P.w2 * ta.w + P.w3 * tb.x + P.w4 * tb.y;
        float s2 = P.w0 * ta.z + P.w1 * ta.w + P.w2 * tb.x + P.w3 * tb.y + P.w4 * tb.z;
        float s3 = P.w0 * ta.w + P.w1 * tb.x + P.w2 * tb.y + P.w3 * tb.z + P.w4 * tb.w;
        size_t o = (size_t)(y0 + yy) * WW + (x0 + x);
        float4 nz = *(const float4*)(npz + o);
        *(float4*)(op + o) = make_float4(s0 + 0.05f * nz.x, s1 + 0.05f * nz.y,
                                         s2 + 0.05f * nz.z, s3 + 0.05f * nz.w);
    }
}

extern "C" void kernel_launch(void* const* d_in, const int* in_sizes, int n_in,
                              void* d_out, int out_size, void* d_ws, size_t ws_size,
                              hipStream_t stream) {
    const float* M           = (const float*)d_in[0];
    const int*   channel_idx = (const int*)d_in[1];
    const float* aug_u       = (const float*)d_in[2];
    const float* noise       = (const float*)d_in[3];
    float* out = (float*)d_out;

    const int n_aug = in_sizes[1];
    const int b     = in_sizes[2] / (n_aug * 7);
    const int c     = in_sizes[0] / (b * HH * WW);
    const int N     = b * n_aug;

    int* amap = (int*)d_ws;
    ImgParams* params = (ImgParams*)((char*)d_ws + 4096);

    amap_kernel<<<1, 256, 0, stream>>>(channel_idx, n_aug, c, amap);
    params_kernel<<<(N + 255) / 256, 256, 0, stream>>>(aug_u, params, N);

    dim3 grid(49, c, b);
    fused_kernel<<<grid, 256, 0, stream>>>(M, amap, params, noise, out, c, n_aug);
}